// Round 7
// baseline (211.827 us; speedup 1.0000x reference)
//
#include <hip/hip_runtime.h>

// ---------------- problem constants ----------------
#define B_SAMPLES 8192
#define HID       512
#define NCLS      10
#define STYLE_D   64
#define LATENT_D  16

#define RPB 32                             // rows per block (sorted domain)
#define MAXT    (B_SAMPLES/RPB + NCLS)     // 266 worst-case row tiles
#define MAXROWS (B_SAMPLES + NCLS*RPB)     // 8512 padded sorted rows

typedef short v8s __attribute__((ext_vector_type(8)));
typedef float v4f __attribute__((ext_vector_type(4)));

__device__ __forceinline__ short f2bf(float f) {
    union { float f; unsigned u; } x; x.f = f;
    unsigned r = x.u + 0x7fffu + ((x.u >> 16) & 1u);   // RNE; inputs finite
    return (short)(r >> 16);
}

// swizzled half-index into act[32][512]: XOR 16B-chunk within each 64-elem slice
// (kills the 16-row stride-1KB bank conflict on A-fragment ds_read_b128)
__device__ __forceinline__ int aoff(int m, int k) {
    return m * 512 + (k & ~63) + (((((k >> 3) & 7) ^ (m & 7))) << 3) + (k & 7);
}

// ---------------- grouping (one block) ----------------
__global__ void build_groups(const int* __restrict__ y, int* __restrict__ tclass,
                             int* __restrict__ order) {
    __shared__ int cnt[NCLS], cur[NCLS];
    int t = threadIdx.x;                       // 1024 threads
    if (t < NCLS) cnt[t] = 0;
    __syncthreads();
    for (int b = t; b < B_SAMPLES; b += 1024) atomicAdd(&cnt[y[b]], 1);
    __syncthreads();
    if (t == 0) {
        int off = 0, tt = 0;
        for (int c = 0; c < NCLS; ++c) {
            cur[c] = off;
            int nt = (cnt[c] + RPB - 1) / RPB;
            for (int j = 0; j < nt; ++j) tclass[tt++] = c;
            off += nt * RPB;
        }
        for (int u = tt; u < MAXT; ++u) tclass[u] = -1;
    }
    __syncthreads();
    for (int i = t; i < MAXROWS; i += 1024) order[i] = -1;
    __syncthreads();
    for (int b = t; b < B_SAMPLES; b += 1024) {
        int c = y[b];
        int p = atomicAdd(&cur[c], 1);
        order[p] = b;
    }
}

// wt0 [512][64] bf16: transposed sw0, K-padded (plain layout — no LDS staging now)
__global__ void prep_wt0(const float* __restrict__ sw0, short* __restrict__ wt0) {
    int idx = blockIdx.x * 256 + threadIdx.x;  // 512*64
    int n = idx >> 6, k = idx & 63;
    wt0[idx] = f2bf(k < LATENT_D ? sw0[(size_t)k * HID + n] : 0.f);
}

// mega transpose, plain [n][k] bf16 output. grid (20,16,34).
__global__ void transpose_mega(const float* __restrict__ sw1, const float* __restrict__ sw2,
                               const float* __restrict__ sw3, const float* __restrict__ uw0,
                               const float* __restrict__ uw1, const float* __restrict__ uw2,
                               const float* __restrict__ uw3,
                               short* __restrict__ wt1, short* __restrict__ wt2,
                               short* __restrict__ wt3, short* __restrict__ wtu0,
                               short* __restrict__ wtu1, short* __restrict__ wtu2,
                               short* __restrict__ wtu3) {
    __shared__ float tile[32][33];
    int zz = blockIdx.z;
    int tx = threadIdx.x, ty = threadIdx.y;    // 32 x 8
    if (zz == 33) {
        int cls = blockIdx.x >> 1;             // 0..9
        int n0 = (blockIdx.x & 1) * 32, k0 = blockIdx.y * 32;
        const float* s = uw3  + (size_t)cls * HID * STYLE_D;
        short*       d = wtu3 + (size_t)cls * STYLE_D * HID;
        #pragma unroll
        for (int j = 0; j < 32; j += 8)
            tile[ty + j][tx] = s[(size_t)(k0 + ty + j) * STYLE_D + n0 + tx];
        __syncthreads();
        #pragma unroll
        for (int j = 0; j < 32; j += 8)
            d[(size_t)(n0 + ty + j) * HID + k0 + tx] = f2bf(tile[tx][ty + j]);
        return;
    }
    if (blockIdx.x >= 16) return;
    const float* s; short* d;
    if      (zz == 0) { s = sw1; d = wt1; }
    else if (zz == 1) { s = sw2; d = wt2; }
    else if (zz == 2) { s = sw3; d = wt3; }
    else if (zz < 13) { size_t o = (size_t)(zz - 3)  * HID * HID; s = uw0 + o; d = wtu0 + o; }
    else if (zz < 23) { size_t o = (size_t)(zz - 13) * HID * HID; s = uw1 + o; d = wtu1 + o; }
    else              { size_t o = (size_t)(zz - 23) * HID * HID; s = uw2 + o; d = wtu2 + o; }
    int n0 = blockIdx.x * 32, k0 = blockIdx.y * 32;
    #pragma unroll
    for (int j = 0; j < 32; j += 8)
        tile[ty + j][tx] = s[(size_t)(k0 + ty + j) * HID + n0 + tx];
    __syncthreads();
    #pragma unroll
    for (int j = 0; j < 32; j += 8)
        d[(size_t)(n0 + ty + j) * HID + k0 + tx] = f2bf(tile[tx][ty + j]);
}

// ---------------- one fused layer: weights global->VGPR, act in LDS ----------------
// Wave wv owns output cols [wv*64, wv*64+64). Each B element feeds exactly one
// lane (B[k=8*(l>>4)+j][n=l&15]) -> no LDS, no barriers during the K loop.
template <int KSRC, int NSTEPS>
__device__ __forceinline__ void layer_reg(
    const short* __restrict__ Wv,    // W + nb*KSRC (this wave's 64 rows)
    const float* __restrict__ bs,    // bias (full N)
    short* act, int nb, int lrow, int lko) {
    v4f acc[2][4] = {};
    #pragma unroll 1
    for (int ks = 0; ks < NSTEPS; ++ks) {
        v8s bq[2][4];
        #pragma unroll
        for (int kk = 0; kk < 2; ++kk)
            #pragma unroll
            for (int j = 0; j < 4; ++j)
                bq[kk][j] = *(const v8s*)(Wv + (size_t)(j * 16 + lrow) * KSRC
                                             + ks * 64 + kk * 32 + lko * 8);
        #pragma unroll
        for (int kk = 0; kk < 2; ++kk) {
            v8s af0 = *(const v8s*)&act[aoff(lrow,      ks * 64 + kk * 32 + lko * 8)];
            v8s af1 = *(const v8s*)&act[aoff(16 + lrow, ks * 64 + kk * 32 + lko * 8)];
            #pragma unroll
            for (int j = 0; j < 4; ++j) {
                acc[0][j] = __builtin_amdgcn_mfma_f32_16x16x32_bf16(af0, bq[kk][j], acc[0][j], 0, 0, 0);
                acc[1][j] = __builtin_amdgcn_mfma_f32_16x16x32_bf16(af1, bq[kk][j], acc[1][j], 0, 0, 0);
            }
        }
    }
    __syncthreads();                 // all waves done READING act
    #pragma unroll
    for (int j = 0; j < 4; ++j) {
        float b = bs[nb + j * 16 + lrow];
        #pragma unroll
        for (int i = 0; i < 2; ++i)
            #pragma unroll
            for (int q = 0; q < 4; ++q) {
                int m = i * 16 + lko * 4 + q;         // C/D: row=(l>>4)*4+reg
                int n = nb + j * 16 + lrow;           //      col=l&15
                act[aoff(m, n)] = f2bf(fmaxf(acc[i][j][q] + b, 0.f));
            }
    }
    __syncthreads();                 // writes visible to all waves
}

// ---------------- fused 8-layer megakernel (32 KB LDS, 2 blocks/CU) ----------------
__global__ __launch_bounds__(512, 4) void fused_mlp(
    const float* __restrict__ z, const int* __restrict__ order,
    const int* __restrict__ tclass,
    const short* __restrict__ wt0, const short* __restrict__ wt1,
    const short* __restrict__ wt2, const short* __restrict__ wt3,
    const short* __restrict__ wtu0, const short* __restrict__ wtu1,
    const short* __restrict__ wtu2, const short* __restrict__ wtu3,
    const float* __restrict__ sb0, const float* __restrict__ sb1,
    const float* __restrict__ sb2, const float* __restrict__ sb3,
    const float* __restrict__ ub0, const float* __restrict__ ub1,
    const float* __restrict__ ub2, const float* __restrict__ ub3,
    float* __restrict__ out) {

    const int tile = blockIdx.x;
    const int cls = tclass[tile];
    if (cls < 0) return;
    const int p0 = tile * RPB;

    __shared__ short act[RPB * HID];           // 32 KB

    const int t = threadIdx.x, lane = t & 63, wv = t >> 6;
    const int lrow = lane & 15, lko = lane >> 4;
    const int nb = wv * 64;

    // layer-0 input: gather z rows into act (K-padded to 64, swizzled)
    #pragma unroll
    for (int i = 0; i < 4; ++i) {
        int idx = i * 512 + t;                 // 32 rows x 64 k
        int m = idx >> 6, k = idx & 63;
        int o = order[p0 + m];
        float v = (o >= 0 && k < LATENT_D) ? z[(size_t)o * LATENT_D + k] : 0.f;
        act[aoff(m, k)] = f2bf(v);
    }
    __syncthreads();

    layer_reg<64, 1> (wt0 + (size_t)nb * 64,  sb0, act, nb, lrow, lko);
    layer_reg<512, 8>(wt1 + (size_t)nb * 512, sb1, act, nb, lrow, lko);
    layer_reg<512, 8>(wt2 + (size_t)nb * 512, sb2, act, nb, lrow, lko);
    layer_reg<512, 8>(wt3 + (size_t)nb * 512, sb3, act, nb, lrow, lko);
    layer_reg<512, 8>(wtu0 + (size_t)cls * HID * HID + (size_t)nb * 512,
                      ub0 + cls * HID, act, nb, lrow, lko);
    layer_reg<512, 8>(wtu1 + (size_t)cls * HID * HID + (size_t)nb * 512,
                      ub1 + cls * HID, act, nb, lrow, lko);
    layer_reg<512, 8>(wtu2 + (size_t)cls * HID * HID + (size_t)nb * 512,
                      ub2 + cls * HID, act, nb, lrow, lko);

    // layer 7: N=64, K=512, no relu, fp32 scatter to out (waves 0-3; no barriers)
    if (wv < 4) {
        const short* W = wtu3 + (size_t)cls * STYLE_D * HID;
        const int n2 = wv * 16 + lrow;
        v4f acc[2] = {};
        #pragma unroll 1
        for (int ks = 0; ks < 8; ++ks) {
            #pragma unroll
            for (int kk = 0; kk < 2; ++kk) {
                v8s b   = *(const v8s*)(W + (size_t)n2 * HID + ks * 64 + kk * 32 + lko * 8);
                v8s af0 = *(const v8s*)&act[aoff(lrow,      ks * 64 + kk * 32 + lko * 8)];
                v8s af1 = *(const v8s*)&act[aoff(16 + lrow, ks * 64 + kk * 32 + lko * 8)];
                acc[0] = __builtin_amdgcn_mfma_f32_16x16x32_bf16(af0, b, acc[0], 0, 0, 0);
                acc[1] = __builtin_amdgcn_mfma_f32_16x16x32_bf16(af1, b, acc[1], 0, 0, 0);
            }
        }
        float b = ub3[cls * STYLE_D + n2];
        #pragma unroll
        for (int i = 0; i < 2; ++i)
            #pragma unroll
            for (int q = 0; q < 4; ++q) {
                int m = i * 16 + lko * 4 + q;
                int o = order[p0 + m];
                if (o >= 0) out[(size_t)o * STYLE_D + n2] = acc[i][q] + b;
            }
    }
}

// ---------------- launcher ----------------
extern "C" void kernel_launch(void* const* d_in, const int* in_sizes, int n_in,
                              void* d_out, int out_size, void* d_ws, size_t ws_size,
                              hipStream_t stream) {
    const float* z   = (const float*)d_in[0];
    const int*   y   = (const int*)d_in[1];
    const float* sw0 = (const float*)d_in[2];
    const float* sb0 = (const float*)d_in[3];
    const float* sw1 = (const float*)d_in[4];
    const float* sb1 = (const float*)d_in[5];
    const float* sw2 = (const float*)d_in[6];
    const float* sb2 = (const float*)d_in[7];
    const float* sw3 = (const float*)d_in[8];
    const float* sb3 = (const float*)d_in[9];
    const float* uw0 = (const float*)d_in[10];
    const float* ub0 = (const float*)d_in[11];
    const float* uw1 = (const float*)d_in[12];
    const float* ub1 = (const float*)d_in[13];
    const float* uw2 = (const float*)d_in[14];
    const float* ub2 = (const float*)d_in[15];
    const float* uw3 = (const float*)d_in[16];
    const float* ub3 = (const float*)d_in[17];

    char* p = (char*)d_ws;
    auto alloc = [&](size_t bytes) -> char* {
        char* r = p; p += (bytes + 255) & ~(size_t)255; return r;
    };
    int*   tclass = (int*)alloc(MAXT * 4);
    int*   order  = (int*)alloc(MAXROWS * 4);
    short* wt0    = (short*)alloc((size_t)HID * 64 * 2);
    short* wt1    = (short*)alloc((size_t)HID * HID * 2);
    short* wt2    = (short*)alloc((size_t)HID * HID * 2);
    short* wt3    = (short*)alloc((size_t)HID * HID * 2);
    short* wtu0   = (short*)alloc((size_t)NCLS * HID * HID * 2);
    short* wtu1   = (short*)alloc((size_t)NCLS * HID * HID * 2);
    short* wtu2   = (short*)alloc((size_t)NCLS * HID * HID * 2);
    short* wtu3   = (short*)alloc((size_t)NCLS * STYLE_D * HID * 2);

    build_groups<<<1, 1024, 0, stream>>>(y, tclass, order);
    prep_wt0<<<(HID * 64) / 256, 256, 0, stream>>>(sw0, wt0);
    dim3 tb(32, 8);
    transpose_mega<<<dim3(20, 16, 34), tb, 0, stream>>>(sw1, sw2, sw3, uw0, uw1, uw2, uw3,
                                                        wt1, wt2, wt3, wtu0, wtu1, wtu2, wtu3);

    fused_mlp<<<MAXT, 512, 0, stream>>>(
        z, order, tclass,
        wt0, wt1, wt2, wt3, wtu0, wtu1, wtu2, wtu3,
        sb0, sb1, sb2, sb3, ub0, ub1, ub2, ub3,
        (float*)d_out);
}

// Round 8
// 138.829 us; speedup vs baseline: 1.5258x; 1.5258x over previous
//
#include <hip/hip_runtime.h>

// ---------------- problem constants ----------------
#define B_SAMPLES 8192
#define HID       512
#define NCLS      10
#define STYLE_D   64
#define LATENT_D  16

#define BM 128
#define BN 64
#define BK 64
#define MAXT    (B_SAMPLES/BM + NCLS)     // 74 worst-case expert row tiles
#define MAXROWS (B_SAMPLES + NCLS*BM)     // 9472 padded sorted rows

typedef short v8s __attribute__((ext_vector_type(8)));
typedef float v4f __attribute__((ext_vector_type(4)));

__device__ __forceinline__ short f2bf(float f) {
    union { float f; unsigned u; } x; x.f = f;
    unsigned r = x.u + 0x7fffu + ((x.u >> 16) & 1u);   // RNE; inputs finite
    return (short)(r >> 16);
}

__device__ __forceinline__ void gload16(const short* g, short* l) {
    __builtin_amdgcn_global_load_lds(
        (const __attribute__((address_space(1))) void*)g,
        (__attribute__((address_space(3))) void*)l, 16, 0, 0);
}

// global pre-swizzle: within each 64-elem slice of a row, XOR the 16B chunk
// index with (row&7). Writers store swizzled; global_load_lds copies rows
// linearly; fragment ds_reads XOR the same key -> conflict-free (rule #21).
__device__ __forceinline__ int kswz(int row, int k) {
    return (k & ~63) + ((((k >> 3) & 7) ^ (row & 7)) << 3) + (k & 7);
}
// swizzled column for epilogue stores (n0 64-aligned, c in [0,64))
__device__ __forceinline__ int cswz(int key, int n0, int c) {
    return n0 + ((((c >> 3) ^ key) & 7) << 3) + (c & 7);
}

// ---------------- grouping (one block) ----------------
__global__ void build_groups(const int* __restrict__ y, int* __restrict__ tclass,
                             int* __restrict__ trow0, int* __restrict__ order,
                             int* __restrict__ rank) {
    __shared__ int cnt[NCLS], cur[NCLS];
    int t = threadIdx.x;                       // 1024 threads
    if (t < NCLS) cnt[t] = 0;
    __syncthreads();
    for (int b = t; b < B_SAMPLES; b += 1024) atomicAdd(&cnt[y[b]], 1);
    __syncthreads();
    if (t == 0) {
        int off = 0, tt = 0;
        for (int c = 0; c < NCLS; ++c) {
            cur[c] = off;
            int nt = (cnt[c] + BM - 1) / BM;
            for (int j = 0; j < nt; ++j) { tclass[tt] = c; trow0[tt] = off + j * BM; ++tt; }
            off += nt * BM;
        }
        for (int u = tt; u < MAXT; ++u) { tclass[u] = -1; trow0[u] = 0; }
    }
    __syncthreads();
    for (int i = t; i < MAXROWS; i += 1024) order[i] = -1;
    __syncthreads();
    for (int b = t; b < B_SAMPLES; b += 1024) {
        int c = y[b];
        int p = atomicAdd(&cur[c], 1);
        order[p] = b;
        rank[b] = p;
    }
}

// zb [8192][64] bf16: K-padded z, swizzled rows (key = sample row)
__global__ void prep_zb(const float* __restrict__ z, short* __restrict__ zb) {
    int idx = blockIdx.x * 256 + threadIdx.x;  // 8192*64
    int b = idx >> 6, k = idx & 63;
    zb[b * 64 + kswz(b, k)] = f2bf(k < LATENT_D ? z[(size_t)b * LATENT_D + k] : 0.f);
}

// mega transpose -> bf16 [n][k], PRE-SWIZZLED rows. grid (20,16,35).
// zz<33 (bx<16): 512x512 slices (sw1,sw2,sw3,uw0[10],uw1[10],uw2[10])
// zz==33 (bx<20): uw3 -> [64][512] per class
// zz==34 (bx<16, by<2): sw0 [16][512] -> wt0 [512][64] (K-padded)
__global__ void transpose_mega(const float* __restrict__ sw0, const float* __restrict__ sw1,
                               const float* __restrict__ sw2, const float* __restrict__ sw3,
                               const float* __restrict__ uw0, const float* __restrict__ uw1,
                               const float* __restrict__ uw2, const float* __restrict__ uw3,
                               short* __restrict__ wt0, short* __restrict__ wt1,
                               short* __restrict__ wt2, short* __restrict__ wt3,
                               short* __restrict__ wtu0, short* __restrict__ wtu1,
                               short* __restrict__ wtu2, short* __restrict__ wtu3) {
    __shared__ float tile[32][33];
    int zz = blockIdx.z;
    int tx = threadIdx.x, ty = threadIdx.y;    // 32 x 8
    if (zz == 34) {                            // sw0 -> wt0 [512][64]
        if (blockIdx.x >= 16 || blockIdx.y >= 2) return;
        int n0 = blockIdx.x * 32, k0 = blockIdx.y * 32;
        #pragma unroll
        for (int j = 0; j < 32; j += 8) {
            int k = k0 + ty + j;
            tile[ty + j][tx] = (k < LATENT_D) ? sw0[(size_t)k * HID + n0 + tx] : 0.f;
        }
        __syncthreads();
        #pragma unroll
        for (int j = 0; j < 32; j += 8) {
            int n = n0 + ty + j, k = k0 + tx;
            wt0[n * 64 + kswz(n, k)] = f2bf(tile[tx][ty + j]);
        }
        return;
    }
    if (zz == 33) {                            // uw3 -> wtu3 [10][64][512]
        int cls = blockIdx.x >> 1;             // 0..9
        int n0 = (blockIdx.x & 1) * 32, k0 = blockIdx.y * 32;
        const float* s = uw3  + (size_t)cls * HID * STYLE_D;
        short*       d = wtu3 + (size_t)cls * STYLE_D * HID;
        #pragma unroll
        for (int j = 0; j < 32; j += 8)
            tile[ty + j][tx] = s[(size_t)(k0 + ty + j) * STYLE_D + n0 + tx];
        __syncthreads();
        #pragma unroll
        for (int j = 0; j < 32; j += 8) {
            int n = n0 + ty + j, k = k0 + tx;
            d[(size_t)n * HID + kswz(n, k)] = f2bf(tile[tx][ty + j]);
        }
        return;
    }
    if (blockIdx.x >= 16) return;
    const float* s; short* d;
    if      (zz == 0) { s = sw1; d = wt1; }
    else if (zz == 1) { s = sw2; d = wt2; }
    else if (zz == 2) { s = sw3; d = wt3; }
    else if (zz < 13) { size_t o = (size_t)(zz - 3)  * HID * HID; s = uw0 + o; d = wtu0 + o; }
    else if (zz < 23) { size_t o = (size_t)(zz - 13) * HID * HID; s = uw1 + o; d = wtu1 + o; }
    else              { size_t o = (size_t)(zz - 23) * HID * HID; s = uw2 + o; d = wtu2 + o; }
    int n0 = blockIdx.x * 32, k0 = blockIdx.y * 32;
    #pragma unroll
    for (int j = 0; j < 32; j += 8)
        tile[ty + j][tx] = s[(size_t)(k0 + ty + j) * HID + n0 + tx];
    __syncthreads();
    #pragma unroll
    for (int j = 0; j < 32; j += 8) {
        int n = n0 + ty + j, k = k0 + tx;
        d[(size_t)n * HID + kswz(n, k)] = f2bf(tile[tx][ty + j]);
    }
}

// ---------------- core GEMM: 128x64 tile, BK=64, 2-phase double-buffered ----
// All bf16 operand buffers are pre-swizzled in global (kswz).
// MODE 0: trunk, linear rows, relu, bf16 out (swizzled)
// MODE 1: trunk L3, relu, bf16 out scattered to rank[row] (swizzled)
// MODE 2: expert mid, tile rows, relu, bf16 out (swizzled)
// MODE 3: expert last, tile rows, no relu, fp32 scatter to d_out (plain)
template <int MODE>
__global__ __launch_bounds__(256, 2) void gemm2ph(
    const short* __restrict__ A, const short* __restrict__ WT,
    const float* __restrict__ bias, void* __restrict__ Outv,
    const int N, const int K, const long wStride, const int biasN,
    const int* __restrict__ aux, const int* __restrict__ tclass,
    const int* __restrict__ trow0) {

    int tile = blockIdx.y, cls = 0, row0;
    if (MODE <= 1) {
        row0 = tile * BM;
    } else {
        cls = tclass[tile];
        if (cls < 0) return;               // uniform block exit
        row0 = trow0[tile];
    }
    const int n0 = blockIdx.x * BN;
    const short* wt = WT + (size_t)cls * wStride;
    const float* bs = bias + (size_t)cls * biasN;

    __shared__ short As[2][BM * BK];       // 2 x 16 KB
    __shared__ short Bs[2][BN * BK];       // 2 x  8 KB   -> 48 KB total

    const int t = threadIdx.x, lane = t & 63, w = t >> 6;
    const int srow = lane >> 3, scol = (lane & 7) * 8;   // 8 lanes x 16B per row
    const int wr = w >> 1, wc = w & 1;
    const int lrow = lane & 15, lko = lane >> 4;
    const int key = lrow & 7;              // swizzle key (row&7 == lrow&7 here)

    v4f acc[4][2] = {};

    auto stage = [&](int buf, int k0) {
        #pragma unroll
        for (int p = 0; p < 4; ++p) {
            int row = p * 32 + w * 8 + srow;
            gload16(A + (size_t)(row0 + row) * K + k0 + scol, &As[buf][p * 2048 + w * 512]);
        }
        #pragma unroll
        for (int q = 0; q < 2; ++q) {
            int row = q * 32 + w * 8 + srow;
            gload16(wt + (size_t)(n0 + row) * K + k0 + scol, &Bs[buf][q * 2048 + w * 512]);
        }
    };

    stage(0, 0);
    __syncthreads();
    const int nk = K / BK;
    for (int ks = 0; ks < nk; ++ks) {
        int buf = ks & 1;
        if (ks + 1 < nk) stage(buf ^ 1, (ks + 1) * BK);   // prefetch next tile

        #pragma unroll
        for (int kk = 0; kk < 2; ++kk) {
            int ch = ((kk * 4 + lko) ^ key) << 3;
            v8s af[4], bq[2];
            #pragma unroll
            for (int i = 0; i < 4; ++i)
                af[i] = *(const v8s*)&As[buf][(wr * 64 + i * 16 + lrow) * BK + ch];
            #pragma unroll
            for (int j = 0; j < 2; ++j)
                bq[j] = *(const v8s*)&Bs[buf][(wc * 32 + j * 16 + lrow) * BK + ch];
            #pragma unroll
            for (int i = 0; i < 4; ++i)
                #pragma unroll
                for (int j = 0; j < 2; ++j)
                    acc[i][j] = __builtin_amdgcn_mfma_f32_16x16x32_bf16(
                        af[i], bq[j], acc[i][j], 0, 0, 0);
        }
        __syncthreads();   // drains staged loads (aged under MFMA) + read fence
    }

    // ---- epilogue ----
    #pragma unroll
    for (int i = 0; i < 4; ++i)
        #pragma unroll
        for (int j = 0; j < 2; ++j)
            #pragma unroll
            for (int q = 0; q < 4; ++q) {
                int r = wr * 64 + i * 16 + lko * 4 + q;   // C/D: row=(l>>4)*4+reg
                int c = wc * 32 + j * 16 + lrow;          //      col=l&15
                if (MODE == 3) {
                    int o = aux[row0 + r];                // order (pos -> sample)
                    if (o >= 0)
                        ((float*)Outv)[(size_t)o * STYLE_D + n0 + c] = acc[i][j][q] + bs[n0 + c];
                } else {
                    float v = fmaxf(acc[i][j][q] + bs[n0 + c], 0.f);
                    int orow = (MODE == 1) ? aux[row0 + r] : (row0 + r);  // rank or linear
                    ((short*)Outv)[(size_t)orow * N + cswz(orow & 7, n0, c)] = f2bf(v);
                }
            }
}

// ---------------- launcher ----------------
extern "C" void kernel_launch(void* const* d_in, const int* in_sizes, int n_in,
                              void* d_out, int out_size, void* d_ws, size_t ws_size,
                              hipStream_t stream) {
    const float* z   = (const float*)d_in[0];
    const int*   y   = (const int*)d_in[1];
    const float* sw0 = (const float*)d_in[2];
    const float* sb0 = (const float*)d_in[3];
    const float* sw1 = (const float*)d_in[4];
    const float* sb1 = (const float*)d_in[5];
    const float* sw2 = (const float*)d_in[6];
    const float* sb2 = (const float*)d_in[7];
    const float* sw3 = (const float*)d_in[8];
    const float* sb3 = (const float*)d_in[9];
    const float* uw0 = (const float*)d_in[10];
    const float* ub0 = (const float*)d_in[11];
    const float* uw1 = (const float*)d_in[12];
    const float* ub1 = (const float*)d_in[13];
    const float* uw2 = (const float*)d_in[14];
    const float* ub2 = (const float*)d_in[15];
    const float* uw3 = (const float*)d_in[16];
    const float* ub3 = (const float*)d_in[17];

    char* p = (char*)d_ws;
    auto alloc = [&](size_t bytes) -> char* {
        char* r = p; p += (bytes + 255) & ~(size_t)255; return r;
    };
    int*   tclass = (int*)alloc(MAXT * 4);
    int*   trow0  = (int*)alloc(MAXT * 4);
    int*   order  = (int*)alloc(MAXROWS * 4);
    int*   rank   = (int*)alloc(B_SAMPLES * 4);
    short* zb     = (short*)alloc((size_t)B_SAMPLES * 64 * 2);
    short* wt0    = (short*)alloc((size_t)HID * 64 * 2);
    short* wt1    = (short*)alloc((size_t)HID * HID * 2);
    short* wt2    = (short*)alloc((size_t)HID * HID * 2);
    short* wt3    = (short*)alloc((size_t)HID * HID * 2);
    short* wtu0   = (short*)alloc((size_t)NCLS * HID * HID * 2);
    short* wtu1   = (short*)alloc((size_t)NCLS * HID * HID * 2);
    short* wtu2   = (short*)alloc((size_t)NCLS * HID * HID * 2);
    short* wtu3   = (short*)alloc((size_t)NCLS * STYLE_D * HID * 2);
    short* act0   = (short*)alloc((size_t)MAXROWS * HID * 2);
    short* act1   = (short*)alloc((size_t)MAXROWS * HID * 2);
    short* act2   = (short*)alloc((size_t)MAXROWS * HID * 2);     // sorted trunk out

    // grouping + prep (pad rows of act2 are never written; their garbage only
    // feeds pad rows downstream and is dropped by order<0 at the final scatter)
    build_groups<<<1, 1024, 0, stream>>>(y, tclass, trow0, order, rank);
    prep_zb<<<(B_SAMPLES * 64) / 256, 256, 0, stream>>>(z, zb);
    dim3 tb(32, 8);
    transpose_mega<<<dim3(20, 16, 35), tb, 0, stream>>>(
        sw0, sw1, sw2, sw3, uw0, uw1, uw2, uw3,
        wt0, wt1, wt2, wt3, wtu0, wtu1, wtu2, wtu3);

    // trunk
    gemm2ph<0><<<dim3(HID / BN, B_SAMPLES / BM), 256, 0, stream>>>(
        zb, wt0, sb0, act0, HID, 64, 0, 0, nullptr, nullptr, nullptr);
    gemm2ph<0><<<dim3(HID / BN, B_SAMPLES / BM), 256, 0, stream>>>(
        act0, wt1, sb1, act1, HID, HID, 0, 0, nullptr, nullptr, nullptr);
    gemm2ph<0><<<dim3(HID / BN, B_SAMPLES / BM), 256, 0, stream>>>(
        act1, wt2, sb2, act0, HID, HID, 0, 0, nullptr, nullptr, nullptr);
    gemm2ph<1><<<dim3(HID / BN, B_SAMPLES / BM), 256, 0, stream>>>(
        act0, wt3, sb3, act2, HID, HID, 0, 0, rank, nullptr, nullptr);

    // selected experts (class-grouped, sorted-linear rows)
    gemm2ph<2><<<dim3(HID / BN, MAXT), 256, 0, stream>>>(
        act2, wtu0, ub0, act0, HID, HID, (long)HID * HID, HID,
        nullptr, tclass, trow0);
    gemm2ph<2><<<dim3(HID / BN, MAXT), 256, 0, stream>>>(
        act0, wtu1, ub1, act1, HID, HID, (long)HID * HID, HID,
        nullptr, tclass, trow0);
    gemm2ph<2><<<dim3(HID / BN, MAXT), 256, 0, stream>>>(
        act1, wtu2, ub2, act0, HID, HID, (long)HID * HID, HID,
        nullptr, tclass, trow0);
    gemm2ph<3><<<dim3(1, MAXT), 256, 0, stream>>>(
        act0, wtu3, ub3, d_out, HID, HID, (long)STYLE_D * HID, STYLE_D,
        order, tclass, trow0);
}

// Round 9
// 114.721 us; speedup vs baseline: 1.8465x; 1.2101x over previous
//
#include <hip/hip_runtime.h>

// ---------------- problem constants ----------------
#define B_SAMPLES 8192
#define HID       512
#define NCLS      10
#define STYLE_D   64
#define LATENT_D  16

#define BM 128
#define BN 64
#define BK 64
#define MAXT    (B_SAMPLES/BM + NCLS)     // 74 worst-case expert row tiles
#define MAXROWS (B_SAMPLES + NCLS*BM)     // 9472 padded sorted rows

typedef short v8s __attribute__((ext_vector_type(8)));
typedef float v4f __attribute__((ext_vector_type(4)));

__device__ __forceinline__ short f2bf(float f) {
    union { float f; unsigned u; } x; x.f = f;
    unsigned r = x.u + 0x7fffu + ((x.u >> 16) & 1u);   // RNE; inputs finite
    return (short)(r >> 16);
}

__device__ __forceinline__ void gload16(const short* g, short* l) {
    __builtin_amdgcn_global_load_lds(
        (const __attribute__((address_space(1))) void*)g,
        (__attribute__((address_space(3))) void*)l, 16, 0, 0);
}

// global pre-swizzle: within each 64-elem slice of a row, XOR the 16B chunk
// index with (row&7). Writers store swizzled; global_load_lds copies rows
// linearly; fragment ds_reads XOR the same key -> conflict-free (rule #21).
__device__ __forceinline__ int kswz(int row, int k) {
    return (k & ~63) + ((((k >> 3) & 7) ^ (row & 7)) << 3) + (k & 7);
}
// swizzled column for epilogue stores (n0 64-aligned, c in [0,64))
__device__ __forceinline__ int cswz(int key, int n0, int c) {
    return n0 + ((((c >> 3) ^ key) & 7) << 3) + (c & 7);
}

// ---------------- grouping (one block) ----------------
__global__ void build_groups(const int* __restrict__ y, int* __restrict__ tclass,
                             int* __restrict__ trow0, int* __restrict__ order,
                             int* __restrict__ rank) {
    __shared__ int cnt[NCLS], cur[NCLS];
    int t = threadIdx.x;                       // 1024 threads
    if (t < NCLS) cnt[t] = 0;
    __syncthreads();
    for (int b = t; b < B_SAMPLES; b += 1024) atomicAdd(&cnt[y[b]], 1);
    __syncthreads();
    if (t == 0) {
        int off = 0, tt = 0;
        for (int c = 0; c < NCLS; ++c) {
            cur[c] = off;
            int nt = (cnt[c] + BM - 1) / BM;
            for (int j = 0; j < nt; ++j) { tclass[tt] = c; trow0[tt] = off + j * BM; ++tt; }
            off += nt * BM;
        }
        for (int u = tt; u < MAXT; ++u) { tclass[u] = -1; trow0[u] = 0; }
    }
    __syncthreads();
    for (int i = t; i < MAXROWS; i += 1024) order[i] = -1;
    __syncthreads();
    for (int b = t; b < B_SAMPLES; b += 1024) {
        int c = y[b];
        int p = atomicAdd(&cur[c], 1);
        order[p] = b;
        rank[b] = p;
    }
}

// zb [8192][64] bf16: K-padded z, swizzled rows (key = sample row)
__global__ void prep_zb(const float* __restrict__ z, short* __restrict__ zb) {
    int idx = blockIdx.x * 256 + threadIdx.x;  // 8192*64
    int b = idx >> 6, k = idx & 63;
    zb[b * 64 + kswz(b, k)] = f2bf(k < LATENT_D ? z[(size_t)b * LATENT_D + k] : 0.f);
}

// mega transpose -> bf16 [n][k], PRE-SWIZZLED rows. grid (20,16,35).
__global__ void transpose_mega(const float* __restrict__ sw0, const float* __restrict__ sw1,
                               const float* __restrict__ sw2, const float* __restrict__ sw3,
                               const float* __restrict__ uw0, const float* __restrict__ uw1,
                               const float* __restrict__ uw2, const float* __restrict__ uw3,
                               short* __restrict__ wt0, short* __restrict__ wt1,
                               short* __restrict__ wt2, short* __restrict__ wt3,
                               short* __restrict__ wtu0, short* __restrict__ wtu1,
                               short* __restrict__ wtu2, short* __restrict__ wtu3) {
    __shared__ float tile[32][33];
    int zz = blockIdx.z;
    int tx = threadIdx.x, ty = threadIdx.y;    // 32 x 8
    if (zz == 34) {                            // sw0 -> wt0 [512][64]
        if (blockIdx.x >= 16 || blockIdx.y >= 2) return;
        int n0 = blockIdx.x * 32, k0 = blockIdx.y * 32;
        #pragma unroll
        for (int j = 0; j < 32; j += 8) {
            int k = k0 + ty + j;
            tile[ty + j][tx] = (k < LATENT_D) ? sw0[(size_t)k * HID + n0 + tx] : 0.f;
        }
        __syncthreads();
        #pragma unroll
        for (int j = 0; j < 32; j += 8) {
            int n = n0 + ty + j, k = k0 + tx;
            wt0[n * 64 + kswz(n, k)] = f2bf(tile[tx][ty + j]);
        }
        return;
    }
    if (zz == 33) {                            // uw3 -> wtu3 [10][64][512]
        int cls = blockIdx.x >> 1;             // 0..9
        int n0 = (blockIdx.x & 1) * 32, k0 = blockIdx.y * 32;
        const float* s = uw3  + (size_t)cls * HID * STYLE_D;
        short*       d = wtu3 + (size_t)cls * STYLE_D * HID;
        #pragma unroll
        for (int j = 0; j < 32; j += 8)
            tile[ty + j][tx] = s[(size_t)(k0 + ty + j) * STYLE_D + n0 + tx];
        __syncthreads();
        #pragma unroll
        for (int j = 0; j < 32; j += 8) {
            int n = n0 + ty + j, k = k0 + tx;
            d[(size_t)n * HID + kswz(n, k)] = f2bf(tile[tx][ty + j]);
        }
        return;
    }
    if (blockIdx.x >= 16) return;
    const float* s; short* d;
    if      (zz == 0) { s = sw1; d = wt1; }
    else if (zz == 1) { s = sw2; d = wt2; }
    else if (zz == 2) { s = sw3; d = wt3; }
    else if (zz < 13) { size_t o = (size_t)(zz - 3)  * HID * HID; s = uw0 + o; d = wtu0 + o; }
    else if (zz < 23) { size_t o = (size_t)(zz - 13) * HID * HID; s = uw1 + o; d = wtu1 + o; }
    else              { size_t o = (size_t)(zz - 23) * HID * HID; s = uw2 + o; d = wtu2 + o; }
    int n0 = blockIdx.x * 32, k0 = blockIdx.y * 32;
    #pragma unroll
    for (int j = 0; j < 32; j += 8)
        tile[ty + j][tx] = s[(size_t)(k0 + ty + j) * HID + n0 + tx];
    __syncthreads();
    #pragma unroll
    for (int j = 0; j < 32; j += 8) {
        int n = n0 + ty + j, k = k0 + tx;
        d[(size_t)n * HID + kswz(n, k)] = f2bf(tile[tx][ty + j]);
    }
}

// ---------------- core GEMM: 128x64 tile, BK=64, 2-phase, XCD-chunked ----
// MODE 0: trunk, linear rows, relu, bf16 out (swizzled)
// MODE 1: trunk L3, relu, bf16 out scattered to rank[row] (swizzled)
// MODE 2: expert mid, tile rows, relu, bf16 out (swizzled)
// MODE 3: expert last, tile rows, no relu, fp32 scatter to d_out (plain)
template <int MODE>
__global__ __launch_bounds__(256, 2) void gemm2ph(
    const short* __restrict__ A, const short* __restrict__ WT,
    const float* __restrict__ bias, void* __restrict__ Outv,
    const int N, const int K, const long wStride, const int biasN,
    const int* __restrict__ aux, const int* __restrict__ tclass,
    const int* __restrict__ trow0) {

    // T1: bijective XCD-chunk remap (m204). Dispatch order lin -> XCD lin%8;
    // give each XCD a CONTIGUOUS wgid range so the 8 n-blocks of a row-panel
    // (and consecutive row-panels) share one XCD's L2.
    const unsigned gx = gridDim.x;
    const unsigned nwg = gx * gridDim.y;
    {
        unsigned lin = blockIdx.x + gx * blockIdx.y;
        unsigned q = nwg >> 3, r = nwg & 7, xcd = lin & 7, idx = lin >> 3;
        unsigned wgid = (xcd < r ? xcd * (q + 1) : r * (q + 1) + (xcd - r) * q) + idx;
        lin = wgid;
        // decompose: x fastest
        unsigned bx = lin % gx, by = lin / gx;
        // shadow blockIdx via locals below
        // (gx is 8 or 1; division is uniform-scalar, once per block)
        // store into tile/n0 path:
        int tile = by, cls = 0, row0;
        if (MODE <= 1) {
            row0 = tile * BM;
        } else {
            cls = tclass[tile];
            if (cls < 0) return;               // uniform block exit
            row0 = trow0[tile];
        }
        const int n0 = bx * BN;
        const short* wt = WT + (size_t)cls * wStride;
        const float* bs = bias + (size_t)cls * biasN;

        __shared__ short As[2][BM * BK];       // 2 x 16 KB
        __shared__ short Bs[2][BN * BK];       // 2 x  8 KB   -> 48 KB total

        const int t = threadIdx.x, lane = t & 63, w = t >> 6;
        const int srow = lane >> 3, scol = (lane & 7) * 8;   // 8 lanes x 16B per row
        const int wr = w >> 1, wc = w & 1;
        const int lrow = lane & 15, lko = lane >> 4;
        const int key = lrow & 7;              // swizzle key (row&7 == lrow&7 here)

        v4f acc[4][2] = {};

        auto stage = [&](int buf, int k0) {
            #pragma unroll
            for (int p = 0; p < 4; ++p) {
                int row = p * 32 + w * 8 + srow;
                gload16(A + (size_t)(row0 + row) * K + k0 + scol, &As[buf][p * 2048 + w * 512]);
            }
            #pragma unroll
            for (int q2 = 0; q2 < 2; ++q2) {
                int row = q2 * 32 + w * 8 + srow;
                gload16(wt + (size_t)(n0 + row) * K + k0 + scol, &Bs[buf][q2 * 2048 + w * 512]);
            }
        };

        stage(0, 0);
        __syncthreads();
        const int nk = K / BK;
        for (int ks = 0; ks < nk; ++ks) {
            int buf = ks & 1;
            if (ks + 1 < nk) stage(buf ^ 1, (ks + 1) * BK);   // prefetch next tile

            #pragma unroll
            for (int kk = 0; kk < 2; ++kk) {
                int ch = ((kk * 4 + lko) ^ key) << 3;
                v8s af[4], bq[2];
                #pragma unroll
                for (int i = 0; i < 4; ++i)
                    af[i] = *(const v8s*)&As[buf][(wr * 64 + i * 16 + lrow) * BK + ch];
                #pragma unroll
                for (int j = 0; j < 2; ++j)
                    bq[j] = *(const v8s*)&Bs[buf][(wc * 32 + j * 16 + lrow) * BK + ch];
                #pragma unroll
                for (int i = 0; i < 4; ++i)
                    #pragma unroll
                    for (int j = 0; j < 2; ++j)
                        acc[i][j] = __builtin_amdgcn_mfma_f32_16x16x32_bf16(
                            af[i], bq[j], acc[i][j], 0, 0, 0);
            }
            __syncthreads();   // drains staged loads (aged under MFMA) + read fence
        }

        // ---- epilogue ----
        #pragma unroll
        for (int i = 0; i < 4; ++i)
            #pragma unroll
            for (int j = 0; j < 2; ++j)
                #pragma unroll
                for (int q3 = 0; q3 < 4; ++q3) {
                    int rr = wr * 64 + i * 16 + lko * 4 + q3;  // C/D: row=(l>>4)*4+reg
                    int c = wc * 32 + j * 16 + lrow;           //      col=l&15
                    if (MODE == 3) {
                        int o = aux[row0 + rr];                // order (pos -> sample)
                        if (o >= 0)
                            ((float*)Outv)[(size_t)o * STYLE_D + n0 + c] = acc[i][j][q3] + bs[n0 + c];
                    } else {
                        float v = fmaxf(acc[i][j][q3] + bs[n0 + c], 0.f);
                        int orow = (MODE == 1) ? aux[row0 + rr] : (row0 + rr);
                        ((short*)Outv)[(size_t)orow * N + cswz(orow & 7, n0, c)] = f2bf(v);
                    }
                }
    }
}

// ---------------- launcher ----------------
extern "C" void kernel_launch(void* const* d_in, const int* in_sizes, int n_in,
                              void* d_out, int out_size, void* d_ws, size_t ws_size,
                              hipStream_t stream) {
    const float* z   = (const float*)d_in[0];
    const int*   y   = (const int*)d_in[1];
    const float* sw0 = (const float*)d_in[2];
    const float* sb0 = (const float*)d_in[3];
    const float* sw1 = (const float*)d_in[4];
    const float* sb1 = (const float*)d_in[5];
    const float* sw2 = (const float*)d_in[6];
    const float* sb2 = (const float*)d_in[7];
    const float* sw3 = (const float*)d_in[8];
    const float* sb3 = (const float*)d_in[9];
    const float* uw0 = (const float*)d_in[10];
    const float* ub0 = (const float*)d_in[11];
    const float* uw1 = (const float*)d_in[12];
    const float* ub1 = (const float*)d_in[13];
    const float* uw2 = (const float*)d_in[14];
    const float* ub2 = (const float*)d_in[15];
    const float* uw3 = (const float*)d_in[16];
    const float* ub3 = (const float*)d_in[17];

    char* p = (char*)d_ws;
    auto alloc = [&](size_t bytes) -> char* {
        char* r = p; p += (bytes + 255) & ~(size_t)255; return r;
    };
    int*   tclass = (int*)alloc(MAXT * 4);
    int*   trow0  = (int*)alloc(MAXT * 4);
    int*   order  = (int*)alloc(MAXROWS * 4);
    int*   rank   = (int*)alloc(B_SAMPLES * 4);
    short* zb     = (short*)alloc((size_t)B_SAMPLES * 64 * 2);
    short* wt0    = (short*)alloc((size_t)HID * 64 * 2);
    short* wt1    = (short*)alloc((size_t)HID * HID * 2);
    short* wt2    = (short*)alloc((size_t)HID * HID * 2);
    short* wt3    = (short*)alloc((size_t)HID * HID * 2);
    short* wtu0   = (short*)alloc((size_t)NCLS * HID * HID * 2);
    short* wtu1   = (short*)alloc((size_t)NCLS * HID * HID * 2);
    short* wtu2   = (short*)alloc((size_t)NCLS * HID * HID * 2);
    short* wtu3   = (short*)alloc((size_t)NCLS * STYLE_D * HID * 2);
    short* act0   = (short*)alloc((size_t)MAXROWS * HID * 2);
    short* act1   = (short*)alloc((size_t)MAXROWS * HID * 2);
    short* act2   = (short*)alloc((size_t)MAXROWS * HID * 2);     // sorted trunk out

    build_groups<<<1, 1024, 0, stream>>>(y, tclass, trow0, order, rank);
    prep_zb<<<(B_SAMPLES * 64) / 256, 256, 0, stream>>>(z, zb);
    dim3 tb(32, 8);
    transpose_mega<<<dim3(20, 16, 35), tb, 0, stream>>>(
        sw0, sw1, sw2, sw3, uw0, uw1, uw2, uw3,
        wt0, wt1, wt2, wt3, wtu0, wtu1, wtu2, wtu3);

    // trunk
    gemm2ph<0><<<dim3(HID / BN, B_SAMPLES / BM), 256, 0, stream>>>(
        zb, wt0, sb0, act0, HID, 64, 0, 0, nullptr, nullptr, nullptr);
    gemm2ph<0><<<dim3(HID / BN, B_SAMPLES / BM), 256, 0, stream>>>(
        act0, wt1, sb1, act1, HID, HID, 0, 0, nullptr, nullptr, nullptr);
    gemm2ph<0><<<dim3(HID / BN, B_SAMPLES / BM), 256, 0, stream>>>(
        act1, wt2, sb2, act0, HID, HID, 0, 0, nullptr, nullptr, nullptr);
    gemm2ph<1><<<dim3(HID / BN, B_SAMPLES / BM), 256, 0, stream>>>(
        act0, wt3, sb3, act2, HID, HID, 0, 0, rank, nullptr, nullptr);

    // selected experts (class-grouped, sorted-linear rows)
    gemm2ph<2><<<dim3(HID / BN, MAXT), 256, 0, stream>>>(
        act2, wtu0, ub0, act0, HID, HID, (long)HID * HID, HID,
        nullptr, tclass, trow0);
    gemm2ph<2><<<dim3(HID / BN, MAXT), 256, 0, stream>>>(
        act0, wtu1, ub1, act1, HID, HID, (long)HID * HID, HID,
        nullptr, tclass, trow0);
    gemm2ph<2><<<dim3(HID / BN, MAXT), 256, 0, stream>>>(
        act1, wtu2, ub2, act0, HID, HID, (long)HID * HID, HID,
        nullptr, tclass, trow0);
    gemm2ph<3><<<dim3(1, MAXT), 256, 0, stream>>>(
        act0, wtu3, ub3, d_out, HID, HID, (long)STYLE_D * HID, STYLE_D,
        order, tclass, trow0);
}